// Round 8
// baseline (3120.554 us; speedup 1.0000x reference)
//
#include <hip/hip_runtime.h>
#include <math.h>
#include <stdint.h>

#define SS 2048
#define II 32

typedef _Float16 f16x2 __attribute__((ext_vector_type(2)));
typedef __fp16   g16x2 __attribute__((ext_vector_type(2)));
typedef uint32_t u32x4 __attribute__((ext_vector_type(4)));

union uhc { uint32_t u; f16x2 a; g16x2 b; };

__device__ __forceinline__ uint32_t pk(float x, float y) {
    uhc c; c.b = __builtin_amdgcn_cvt_pkrtz(x, y); return c.u;
}

__device__ __forceinline__ float fdot2(uint32_t a, uint32_t b, float c) {
    uhc x, y; x.u = a; y.u = b;
#if __has_builtin(__builtin_amdgcn_fdot2)
    return __builtin_amdgcn_fdot2(x.a, y.a, c, false);
#else
    return c + (float)x.a.x * (float)y.a.x + (float)x.a.y * (float)y.a.y;
#endif
}
__device__ __forceinline__ float sigm(float x) {
    return __builtin_amdgcn_rcpf(1.f + __expf(-x));
}
__device__ __forceinline__ float tanh_(float x) {
    x = fminf(fmaxf(x, -15.f), 15.f);
    float e = __expf(-2.f * x);
    return (1.f - e) * __builtin_amdgcn_rcpf(1.f + e);
}

// accumulate 4 packed words of one u32x4 against 4 weight words
#define DOT4(W, K, V)                      \
    a0 = fdot2((W)[(K) + 0], (V).x, a0);   \
    a1 = fdot2((W)[(K) + 1], (V).y, a1);   \
    a2 = fdot2((W)[(K) + 2], (V).z, a2);   \
    a3 = fdot2((W)[(K) + 3], (V).w, a3);

__global__ __launch_bounds__(512, 2) void lstm_fused(
    const float* __restrict__ x,
    const float* __restrict__ h_in, const float* __restrict__ c_in,
    const float* __restrict__ Wih0, const float* __restrict__ Whh0,
    const float* __restrict__ bih0, const float* __restrict__ bhh0,
    const float* __restrict__ Wih1, const float* __restrict__ Whh1,
    const float* __restrict__ bih1, const float* __restrict__ bhh1,
    const float* __restrict__ Wh, const float* __restrict__ bh,
    float* __restrict__ out)
{
    __shared__ __align__(16) float    gb[2][512];     // [parity][L*256 + gtype*64 + unit]
    __shared__ __align__(16) uint32_t h0w[2][32];     // packed half2 h0 (word u = units 2u,2u+1)
    __shared__ __align__(16) uint32_t h1w[2][32];
    __shared__ __align__(16) uint32_t xs[2][64][16];  // packed half2 x chunks

    const int b = blockIdx.x, tid = threadIdx.x;
    const int w = tid >> 6, lane = tid & 63;

    const float* xb = x + (size_t)b * SS * II;

    // ---- cell state: wave 0 owns L0 (unit = lane), wave 1 owns L1 ----
    float creg = 0.f, hreg = 0.f;
    if (w == 0) {
        hreg = h_in[b * 64 + lane];
        creg = c_in[b * 64 + lane];
        float o = __shfl_xor(hreg, 1);
        if (!(lane & 1)) h0w[0][lane >> 1] = pk(hreg, o);   // h0(-1), read at it=0
    }
    if (w == 1) {
        hreg = h_in[16384 + b * 64 + lane];
        creg = c_in[16384 + b * 64 + lane];
        float o = __shfl_xor(hreg, 1);
        if (!(lane & 1)) h1w[1][lane >> 1] = pk(hreg, o);   // h1(-1), read at it=1
    }

    // ---- stage x chunk 0 ----
    {
        const float4 v = *(const float4*)(xb + (tid >> 3) * II + (tid & 7) * 4);
        xs[0][tid >> 3][(tid & 7) * 2]     = pk(v.x, v.y);
        xs[0][tid >> 3][(tid & 7) * 2 + 1] = pk(v.z, v.w);
    }

    if (w < 4) {
        // ========== L0 gate waves: gate row = w*64 + lane (gtype = w) ==========
        uint32_t wxx[16], whh[32];
        {
            const float4* s = (const float4*)(Wih0 + (w * 64 + lane) * 32);
            #pragma unroll
            for (int r = 0; r < 8; ++r) { float4 v = s[r]; wxx[2*r] = pk(v.x, v.y); wxx[2*r+1] = pk(v.z, v.w); }
        }
        {
            const float4* s = (const float4*)(Whh0 + (w * 64 + lane) * 64);
            #pragma unroll
            for (int r = 0; r < 16; ++r) { float4 v = s[r]; whh[2*r] = pk(v.x, v.y); whh[2*r+1] = pk(v.z, v.w); }
        }
        const float bias = bih0[w * 64 + lane] + bhh0[w * 64 + lane];
        // w1 doubles as L1 cell wave + head
        float whv = 0.f, bhs = 0.f, pb = 0.f;
        if (w == 1) { whv = Wh[lane]; bhs = bh[0]; }
        __syncthreads();

        #pragma unroll 1
        for (int it = 0; it <= SS; ++it) {
            const int p = it & 1;
            if (it < SS) {
                // volatile named b128 loads: cannot be sunk/scalarized by the compiler
                const volatile u32x4* hs = (const volatile u32x4*)h0w[p];
                const u32x4 h0_ = hs[0], h1_ = hs[1], h2_ = hs[2], h3_ = hs[3];
                const u32x4 h4_ = hs[4], h5_ = hs[5], h6_ = hs[6], h7_ = hs[7];
                const volatile u32x4* xsrc = (const volatile u32x4*)xs[(it >> 6) & 1][it & 63];
                const u32x4 x0_ = xsrc[0], x1_ = xsrc[1], x2_ = xsrc[2], x3_ = xsrc[3];

                float a0 = bias, a1 = 0.f, a2 = 0.f, a3 = 0.f;
                DOT4(wxx,  0, x0_) DOT4(wxx,  4, x1_) DOT4(wxx,  8, x2_) DOT4(wxx, 12, x3_)
                DOT4(whh,  0, h0_) DOT4(whh,  4, h1_) DOT4(whh,  8, h2_) DOT4(whh, 12, h3_)
                DOT4(whh, 16, h4_) DOT4(whh, 20, h5_) DOT4(whh, 24, h6_) DOT4(whh, 28, h7_)
                const float acc = (a0 + a1) + (a2 + a3);
                gb[p][w * 64 + lane] = (w == 2) ? tanh_(acc) : sigm(acc);
            }
            if ((it & 63) == 0 && it + 64 < SS) {
                const int cn = (it >> 6) + 1;
                const float4 v = *(const float4*)(xb + (cn * 64 + (tid >> 3)) * II + (tid & 7) * 4);
                xs[cn & 1][tid >> 3][(tid & 7) * 2]     = pk(v.x, v.y);
                xs[cn & 1][tid >> 3][(tid & 7) * 2 + 1] = pk(v.z, v.w);
            }
            __syncthreads();

            // ---- phase 2: cell updates ----
            if (w == 0 && it < SS) {            // L0 cell: h0(it)
                float gi = gb[p][lane],       gf = gb[p][64 + lane];
                float gg = gb[p][128 + lane], go = gb[p][192 + lane];
                creg = gf * creg + gi * gg;
                hreg = go * tanh_(creg);
                float o = __shfl_xor(hreg, 1);
                if (!(lane & 1)) h0w[(it + 1) & 1][lane >> 1] = pk(hreg, o);
            }
            if (w == 1 && it >= 1) {            // L1 cell: h1(it-1) + head
                float gi = gb[p][256 + lane],       gf = gb[p][320 + lane];
                float gg = gb[p][384 + lane],       go = gb[p][448 + lane];
                creg = gf * creg + gi * gg;
                hreg = go * tanh_(creg);
                float o = __shfl_xor(hreg, 1);
                if (!(lane & 1)) h1w[(it + 1) & 1][lane >> 1] = pk(hreg, o);
                float pv = hreg * whv;
                pv += __shfl_xor(pv, 1);
                pv += __shfl_xor(pv, 2);
                pv += __shfl_xor(pv, 4);
                pv += __shfl_xor(pv, 8);
                pv += __shfl_xor(pv, 16);
                pv += __shfl_xor(pv, 32);
                pv = sigm(pv + bhs);
                const int t1 = it - 1;
                if ((t1 & 63) == lane) pb = pv;
                if ((t1 & 63) == 63) out[b * SS + (t1 & ~63) + lane] = pb;
            }
            __syncthreads();
        }
    } else {
        // ========== L1 gate waves: gate row = (w-4)*64 + lane ==========
        const int row = (w - 4) * 64 + lane;
        uint32_t wA[32], wB[32];
        {
            const float4* s = (const float4*)(Wih1 + row * 64);
            #pragma unroll
            for (int r = 0; r < 16; ++r) { float4 v = s[r]; wA[2*r] = pk(v.x, v.y); wA[2*r+1] = pk(v.z, v.w); }
        }
        {
            const float4* s = (const float4*)(Whh1 + row * 64);
            #pragma unroll
            for (int r = 0; r < 16; ++r) { float4 v = s[r]; wB[2*r] = pk(v.x, v.y); wB[2*r+1] = pk(v.z, v.w); }
        }
        const float bias = bih1[row] + bhh1[row];
        __syncthreads();

        #pragma unroll 1
        for (int it = 0; it <= SS; ++it) {
            const int p = it & 1;
            if (it >= 1) {
                const volatile u32x4* s0 = (const volatile u32x4*)h0w[p];    // h0(it-1)
                const u32x4 a0_ = s0[0], a1_ = s0[1], a2_ = s0[2], a3_ = s0[3];
                const u32x4 a4_ = s0[4], a5_ = s0[5], a6_ = s0[6], a7_ = s0[7];
                const volatile u32x4* s1 = (const volatile u32x4*)h1w[p];    // h1(it-2)
                const u32x4 b0_ = s1[0], b1_ = s1[1], b2_ = s1[2], b3_ = s1[3];
                const u32x4 b4_ = s1[4], b5_ = s1[5], b6_ = s1[6], b7_ = s1[7];

                float a0 = bias, a1 = 0.f, a2 = 0.f, a3 = 0.f;
                DOT4(wA,  0, a0_) DOT4(wA,  4, a1_) DOT4(wA,  8, a2_) DOT4(wA, 12, a3_)
                DOT4(wA, 16, a4_) DOT4(wA, 20, a5_) DOT4(wA, 24, a6_) DOT4(wA, 28, a7_)
                DOT4(wB,  0, b0_) DOT4(wB,  4, b1_) DOT4(wB,  8, b2_) DOT4(wB, 12, b3_)
                DOT4(wB, 16, b4_) DOT4(wB, 20, b5_) DOT4(wB, 24, b6_) DOT4(wB, 28, b7_)
                const float acc = (a0 + a1) + (a2 + a3);
                gb[p][256 + row] = (w == 6) ? tanh_(acc) : sigm(acc);
            }
            if ((it & 63) == 0 && it + 64 < SS) {
                const int cn = (it >> 6) + 1;
                const float4 v = *(const float4*)(xb + (cn * 64 + (tid >> 3)) * II + (tid & 7) * 4);
                xs[cn & 1][tid >> 3][(tid & 7) * 2]     = pk(v.x, v.y);
                xs[cn & 1][tid >> 3][(tid & 7) * 2 + 1] = pk(v.z, v.w);
            }
            __syncthreads();
            // phase 2: no role for L1 gate waves
            __syncthreads();
        }
    }

    // ---- final states: h at 524288 (2,256,64), c at 557056 ----
    if (w == 0) {
        out[524288 + b * 64 + lane] = hreg;            // h[0]
        out[557056 + b * 64 + lane] = creg;            // c[0]
    }
    if (w == 1) {
        out[524288 + 16384 + b * 64 + lane] = hreg;    // h[1]
        out[557056 + 16384 + b * 64 + lane] = creg;    // c[1]
    }
}

extern "C" void kernel_launch(void* const* d_in, const int* in_sizes, int n_in,
                              void* d_out, int out_size, void* d_ws, size_t ws_size,
                              hipStream_t stream) {
    const float* x    = (const float*)d_in[0];
    const float* h0   = (const float*)d_in[1];
    const float* c0   = (const float*)d_in[2];
    const float* Wih0 = (const float*)d_in[3];
    const float* Whh0 = (const float*)d_in[4];
    const float* bih0 = (const float*)d_in[5];
    const float* bhh0 = (const float*)d_in[6];
    const float* Wih1 = (const float*)d_in[7];
    const float* Whh1 = (const float*)d_in[8];
    const float* bih1 = (const float*)d_in[9];
    const float* bhh1 = (const float*)d_in[10];
    const float* Wh   = (const float*)d_in[11];
    const float* bh   = (const float*)d_in[12];
    float* out = (float*)d_out;

    hipLaunchKernelGGL(lstm_fused, dim3(256), dim3(512), 0, stream,
                       x, h0, c0, Wih0, Whh0, bih0, bhh0,
                       Wih1, Whh1, bih1, bhh1, Wh, bh, out);
}

// Round 9
// 2154.871 us; speedup vs baseline: 1.4481x; 1.4481x over previous
//
#include <hip/hip_runtime.h>
#include <math.h>
#include <stdint.h>

#define SS 2048
#define II 32
#define TB 16

typedef _Float16 f16x8  __attribute__((ext_vector_type(8)));
typedef float    f32x4  __attribute__((ext_vector_type(4)));
typedef uint32_t u32x2e __attribute__((ext_vector_type(2)));
typedef uint32_t u32x4e __attribute__((ext_vector_type(4)));
typedef _Float16 f16x2  __attribute__((ext_vector_type(2)));
typedef __fp16   g16x2  __attribute__((ext_vector_type(2)));

union uhc { uint32_t u; f16x2 a; g16x2 b; };
union frag { f16x8 v; uint32_t w[4]; u32x4e q; };

__device__ __forceinline__ uint32_t pk(float x, float y) {
    uhc c; c.b = __builtin_amdgcn_cvt_pkrtz(x, y); return c.u;
}
__device__ __forceinline__ float fdot2(uint32_t a, uint32_t b, float c) {
    uhc x, y; x.u = a; y.u = b;
#if __has_builtin(__builtin_amdgcn_fdot2)
    return __builtin_amdgcn_fdot2(x.a, y.a, c, false);
#else
    return c + (float)x.a.x * (float)y.a.x + (float)x.a.y * (float)y.a.y;
#endif
}
__device__ __forceinline__ float sigm(float x) { return __builtin_amdgcn_rcpf(1.f + __expf(-x)); }
__device__ __forceinline__ float tanh_(float x) {
    x = fminf(fmaxf(x, -15.f), 15.f);
    float e = __expf(-2.f * x);
    return (1.f - e) * __builtin_amdgcn_rcpf(1.f + e);
}
// pack 8 consecutive f32 -> f16x8 fragment
__device__ __forceinline__ frag load8(const float* p) {
    float4 v0 = ((const float4*)p)[0];
    float4 v1 = ((const float4*)p)[1];
    frag f;
    f.w[0] = pk(v0.x, v0.y); f.w[1] = pk(v0.z, v0.w);
    f.w[2] = pk(v1.x, v1.y); f.w[3] = pk(v1.z, v1.w);
    return f;
}
#define MFMA(A, B, C) __builtin_amdgcn_mfma_f32_16x16x32_f16((A).v, (B).v, (C), 0, 0, 0)

// stage one 16-step x chunk into xsb[(c)&1]: slot(s,l) = x[k=(l>>4)*8..+7][batch=l&15], f16
#define STAGE(c) do {                                                               \
    const int t0_ = (c) * 16;                                                       \
    _Pragma("unroll")                                                               \
    for (int rep_ = 0; rep_ < 2; ++rep_) {                                          \
        int sl_ = tid + rep_ * 512;                                                 \
        int s_ = sl_ >> 6, l_ = sl_ & 63, bb_ = l_ & 15, gg_ = l_ >> 4;             \
        const float* p_ = x + (size_t)(bbase + bb_) * (SS * II)                     \
                          + (size_t)(t0_ + s_) * II + gg_ * 8;                      \
        float4 v0_ = ((const float4*)p_)[0];                                        \
        float4 v1_ = ((const float4*)p_)[1];                                        \
        u32x4e wv_ = { pk(v0_.x, v0_.y), pk(v0_.z, v0_.w),                          \
                       pk(v1_.x, v1_.y), pk(v1_.z, v1_.w) };                        \
        *(u32x4e*)((char*)&xsb[(c) & 1][s_][0] + l_ * 16) = wv_;                    \
    } } while (0)

__global__ __launch_bounds__(512, 2) void lstm_mfma(
    const float* __restrict__ x,
    const float* __restrict__ h_in, const float* __restrict__ c_in,
    const float* __restrict__ Wih0, const float* __restrict__ Whh0,
    const float* __restrict__ bih0, const float* __restrict__ bhh0,
    const float* __restrict__ Wih1, const float* __restrict__ Whh1,
    const float* __restrict__ bih1, const float* __restrict__ bhh1,
    const float* __restrict__ Wh, const float* __restrict__ bh,
    float* __restrict__ out)
{
    // hbuf[parity][layer]: h as packed f16, slot layout (kgroup*16+batch)*16B, kt offset 1024B
    __shared__ uint32_t hbuf[2][2][512];
    __shared__ uint32_t xsb[2][16][256];   // [chunk parity][step][lane*16B]
    __shared__ float    pbuf[64][16];      // probs ring [t&63][batch]

    const int tid = threadIdx.x;
    const int w   = tid >> 6, L = tid & 63;
    const int wl  = w & 3;                 // unit-block within layer group
    const int g16 = L >> 4, b16 = L & 15;
    const int bbase = blockIdx.x * TB;
    const int isL1  = (w >= 4);
    const int u0    = 16 * wl + g16 * 4;   // first of this lane's 4 units
    const int hoff  = ((u0 >> 3) * 16 + b16) * 16 + (u0 & 7) * 2;  // byte offset of lane's h-write

    // ---- initial state (lane owns units u0..u0+3 of batch b16) ----
    const int loff = isL1 ? 16384 : 0;
    const int gbat = bbase + b16;
    float4 h4 = *(const float4*)(h_in + loff + gbat * 64 + u0);
    float4 c4 = *(const float4*)(c_in + loff + gbat * 64 + u0);
    float cst0 = c4.x, cst1 = c4.y, cst2 = c4.z, cst3 = c4.w;
    float hst0 = h4.x, hst1 = h4.y, hst2 = h4.z, hst3 = h4.w;
    {   // h(-1) -> parity-1 buffer
        u32x2e wv = { pk(hst0, hst1), pk(hst2, hst3) };
        *(u32x2e*)((char*)&hbuf[1][isL1][0] + hoff) = wv;
    }
    STAGE(0);
    __syncthreads();

    if (!isL1) {
        // ================= layer-0 group: units 16wl..16wl+15, all 4 gate types =================
        frag aH[4][2], aX[4];
        f32x4 bias4[4];
        #pragma unroll
        for (int t = 0; t < 4; ++t) {
            const int arow = t * 64 + 16 * wl + b16;      // A row for this lane
            aH[t][0] = load8(Whh0 + arow * 64 + g16 * 8);
            aH[t][1] = load8(Whh0 + arow * 64 + 32 + g16 * 8);
            aX[t]    = load8(Wih0 + arow * 32 + g16 * 8);
            const int brow = t * 64 + u0;                 // bias rows follow C layout
            float4 q1 = *(const float4*)(bih0 + brow);
            float4 q2 = *(const float4*)(bhh0 + brow);
            bias4[t] = (f32x4){q1.x + q2.x, q1.y + q2.y, q1.z + q2.z, q1.w + q2.w};
        }

        #pragma unroll 1
        for (int it = 0; it <= SS + 1; ++it) {
            if (it < SS) {
                const char* hb = (const char*)&hbuf[(it + 1) & 1][0][0];   // h0(it-1)
                frag bh0, bh1, bx;
                bh0.v = *(const f16x8*)(hb + L * 16);
                bh1.v = *(const f16x8*)(hb + 1024 + L * 16);
                bx.v  = *(const f16x8*)((const char*)&xsb[(it >> 4) & 1][it & 15][0] + L * 16);
                f32x4 a0 = bias4[0], a1 = bias4[1], a2 = bias4[2], a3 = bias4[3];
                a0 = MFMA(aH[0][0], bh0, a0); a1 = MFMA(aH[1][0], bh0, a1);
                a2 = MFMA(aH[2][0], bh0, a2); a3 = MFMA(aH[3][0], bh0, a3);
                a0 = MFMA(aH[0][1], bh1, a0); a1 = MFMA(aH[1][1], bh1, a1);
                a2 = MFMA(aH[2][1], bh1, a2); a3 = MFMA(aH[3][1], bh1, a3);
                a0 = MFMA(aX[0], bx, a0);     a1 = MFMA(aX[1], bx, a1);
                a2 = MFMA(aX[2], bx, a2);     a3 = MFMA(aX[3], bx, a3);
                // in-register cell update (lane holds i,f,g,o for its 4 units)
                {
                    float i_ = sigm(a0[0]), f_ = sigm(a1[0]), g_ = tanh_(a2[0]), o_ = sigm(a3[0]);
                    cst0 = f_ * cst0 + i_ * g_; hst0 = o_ * tanh_(cst0);
                }
                {
                    float i_ = sigm(a0[1]), f_ = sigm(a1[1]), g_ = tanh_(a2[1]), o_ = sigm(a3[1]);
                    cst1 = f_ * cst1 + i_ * g_; hst1 = o_ * tanh_(cst1);
                }
                {
                    float i_ = sigm(a0[2]), f_ = sigm(a1[2]), g_ = tanh_(a2[2]), o_ = sigm(a3[2]);
                    cst2 = f_ * cst2 + i_ * g_; hst2 = o_ * tanh_(cst2);
                }
                {
                    float i_ = sigm(a0[3]), f_ = sigm(a1[3]), g_ = tanh_(a2[3]), o_ = sigm(a3[3]);
                    cst3 = f_ * cst3 + i_ * g_; hst3 = o_ * tanh_(cst3);
                }
                u32x2e wv = { pk(hst0, hst1), pk(hst2, hst3) };
                *(u32x2e*)((char*)&hbuf[it & 1][0][0] + hoff) = wv;       // h0(it)
            }
            if ((it & 15) == 0 && it + 16 < SS) STAGE((it >> 4) + 1);
            __syncthreads();
        }
    } else {
        // ================= layer-1 group (1-step skew): computes step it-1 at iter it =================
        frag aI[4][2], aR[4][2];
        f32x4 bias4[4];
        #pragma unroll
        for (int t = 0; t < 4; ++t) {
            const int arow = t * 64 + 16 * wl + b16;
            aI[t][0] = load8(Wih1 + arow * 64 + g16 * 8);
            aI[t][1] = load8(Wih1 + arow * 64 + 32 + g16 * 8);
            aR[t][0] = load8(Whh1 + arow * 64 + g16 * 8);
            aR[t][1] = load8(Whh1 + arow * 64 + 32 + g16 * 8);
            const int brow = t * 64 + u0;
            float4 q1 = *(const float4*)(bih1 + brow);
            float4 q2 = *(const float4*)(bhh1 + brow);
            bias4[t] = (f32x4){q1.x + q2.x, q1.y + q2.y, q1.z + q2.z, q1.w + q2.w};
        }
        // head (wave 4): Wh slices matching this lane's B k-coverage
        frag whA, whB;
        whA = load8(Wh + g16 * 8);
        whB = load8(Wh + 32 + g16 * 8);
        const float bhs = bh[0];

        #pragma unroll 1
        for (int it = 0; it <= SS + 1; ++it) {
            frag b1, b1k;
            if (it >= 1) {                                   // h1(it-2), used by MFMA and head
                const char* h1b = (const char*)&hbuf[it & 1][1][0];
                b1.v  = *(const f16x8*)(h1b + L * 16);
                b1k.v = *(const f16x8*)(h1b + 1024 + L * 16);
            }
            if (it >= 1 && it <= SS) {
                const char* h0b = (const char*)&hbuf[(it + 1) & 1][0][0];  // h0(it-1)
                frag b0, b0k;
                b0.v  = *(const f16x8*)(h0b + L * 16);
                b0k.v = *(const f16x8*)(h0b + 1024 + L * 16);
                f32x4 a0 = bias4[0], a1 = bias4[1], a2 = bias4[2], a3 = bias4[3];
                a0 = MFMA(aI[0][0], b0, a0);  a1 = MFMA(aI[1][0], b0, a1);
                a2 = MFMA(aI[2][0], b0, a2);  a3 = MFMA(aI[3][0], b0, a3);
                a0 = MFMA(aI[0][1], b0k, a0); a1 = MFMA(aI[1][1], b0k, a1);
                a2 = MFMA(aI[2][1], b0k, a2); a3 = MFMA(aI[3][1], b0k, a3);
                a0 = MFMA(aR[0][0], b1, a0);  a1 = MFMA(aR[1][0], b1, a1);
                a2 = MFMA(aR[2][0], b1, a2);  a3 = MFMA(aR[3][0], b1, a3);
                a0 = MFMA(aR[0][1], b1k, a0); a1 = MFMA(aR[1][1], b1k, a1);
                a2 = MFMA(aR[2][1], b1k, a2); a3 = MFMA(aR[3][1], b1k, a3);
                {
                    float i_ = sigm(a0[0]), f_ = sigm(a1[0]), g_ = tanh_(a2[0]), o_ = sigm(a3[0]);
                    cst0 = f_ * cst0 + i_ * g_; hst0 = o_ * tanh_(cst0);
                }
                {
                    float i_ = sigm(a0[1]), f_ = sigm(a1[1]), g_ = tanh_(a2[1]), o_ = sigm(a3[1]);
                    cst1 = f_ * cst1 + i_ * g_; hst1 = o_ * tanh_(cst1);
                }
                {
                    float i_ = sigm(a0[2]), f_ = sigm(a1[2]), g_ = tanh_(a2[2]), o_ = sigm(a3[2]);
                    cst2 = f_ * cst2 + i_ * g_; hst2 = o_ * tanh_(cst2);
                }
                {
                    float i_ = sigm(a0[3]), f_ = sigm(a1[3]), g_ = tanh_(a2[3]), o_ = sigm(a3[3]);
                    cst3 = f_ * cst3 + i_ * g_; hst3 = o_ * tanh_(cst3);
                }
                u32x2e wv = { pk(hst0, hst1), pk(hst2, hst3) };
                *(u32x2e*)((char*)&hbuf[(it + 1) & 1][1][0] + hoff) = wv;  // h1(it-1)
            }
            if (w == 4 && it >= 2) {
                // head for step t = it-2 using h1(it-2) already in b1/b1k
                float pv = 0.f;
                #pragma unroll
                for (int i = 0; i < 4; ++i) {
                    pv = fdot2(whA.w[i], b1.w[i], pv);
                    pv = fdot2(whB.w[i], b1k.w[i], pv);
                }
                pv += __shfl_xor(pv, 16);
                pv += __shfl_xor(pv, 32);
                pv = sigm(pv + bhs);
                const int t = it - 2;
                if (L < 16) pbuf[t & 63][L] = pv;
                if ((t & 63) == 63) {                       // coalesced flush of 64 steps
                    const int tbase = t & ~63;
                    const int fb = L >> 2, fs = (L & 3) * 16;
                    float* gp = out + (size_t)(bbase + fb) * SS + tbase + fs;
                    #pragma unroll
                    for (int q = 0; q < 16; q += 4) {
                        float4 vv = make_float4(pbuf[fs + q][fb], pbuf[fs + q + 1][fb],
                                                pbuf[fs + q + 2][fb], pbuf[fs + q + 3][fb]);
                        *(float4*)(gp + q) = vv;
                    }
                }
            }
            if ((it & 15) == 0 && it + 16 < SS) STAGE((it >> 4) + 1);
            __syncthreads();
        }
    }

    // ---- final states: h at 524288 (2,256,64), c at 557056 ----
    *(float4*)(out + 524288 + loff + gbat * 64 + u0) = make_float4(hst0, hst1, hst2, hst3);
    *(float4*)(out + 557056 + loff + gbat * 64 + u0) = make_float4(cst0, cst1, cst2, cst3);
}

extern "C" void kernel_launch(void* const* d_in, const int* in_sizes, int n_in,
                              void* d_out, int out_size, void* d_ws, size_t ws_size,
                              hipStream_t stream) {
    const float* x    = (const float*)d_in[0];
    const float* h0   = (const float*)d_in[1];
    const float* c0   = (const float*)d_in[2];
    const float* Wih0 = (const float*)d_in[3];
    const float* Whh0 = (const float*)d_in[4];
    const float* bih0 = (const float*)d_in[5];
    const float* bhh0 = (const float*)d_in[6];
    const float* Wih1 = (const float*)d_in[7];
    const float* Whh1 = (const float*)d_in[8];
    const float* bih1 = (const float*)d_in[9];
    const float* bhh1 = (const float*)d_in[10];
    const float* Wh   = (const float*)d_in[11];
    const float* bh   = (const float*)d_in[12];
    float* out = (float*)d_out;

    hipLaunchKernelGGL(lstm_mfma, dim3(256 / TB), dim3(512), 0, stream,
                       x, h0, c0, Wih0, Whh0, bih0, bhh0,
                       Wih1, Whh1, bih1, bhh1, Wh, bh, out);
}

// Round 10
// 1389.241 us; speedup vs baseline: 2.2462x; 1.5511x over previous
//
#include <hip/hip_runtime.h>
#include <math.h>
#include <stdint.h>

#define SS 2048
#define II 32
#define TB 4

typedef _Float16 f16x8  __attribute__((ext_vector_type(8)));
typedef float    f32x4  __attribute__((ext_vector_type(4)));
typedef uint32_t u32x4e __attribute__((ext_vector_type(4)));
typedef _Float16 f16x2  __attribute__((ext_vector_type(2)));
typedef __fp16   g16x2  __attribute__((ext_vector_type(2)));

union uhc { uint32_t u; f16x2 a; g16x2 b; };
union frag { f16x8 v; uint32_t w[4]; u32x4e q; };

__device__ __forceinline__ uint32_t pk(float x, float y) {
    uhc c; c.b = __builtin_amdgcn_cvt_pkrtz(x, y); return c.u;
}
__device__ __forceinline__ float fdot2(uint32_t a, uint32_t b, float c) {
    uhc x, y; x.u = a; y.u = b;
#if __has_builtin(__builtin_amdgcn_fdot2)
    return __builtin_amdgcn_fdot2(x.a, y.a, c, false);
#else
    return c + (float)x.a.x * (float)y.a.x + (float)x.a.y * (float)y.a.y;
#endif
}
__device__ __forceinline__ float sigm(float x) { return __builtin_amdgcn_rcpf(1.f + __expf(-x)); }
__device__ __forceinline__ float tanh_(float x) {
    x = fminf(fmaxf(x, -15.f), 15.f);
    float e = __expf(-2.f * x);
    return (1.f - e) * __builtin_amdgcn_rcpf(1.f + e);
}
__device__ __forceinline__ frag load8(const float* p) {
    float4 v0 = ((const float4*)p)[0];
    float4 v1 = ((const float4*)p)[1];
    frag f;
    f.w[0] = pk(v0.x, v0.y); f.w[1] = pk(v0.z, v0.w);
    f.w[2] = pk(v1.x, v1.y); f.w[3] = pk(v1.z, v1.w);
    return f;
}
#define MFMA(A, B, C) __builtin_amdgcn_mfma_f32_16x16x32_f16((A).v, (B).v, (C), 0, 0, 0)
// extract component j (runtime 0..3, per-lane uniform) from f32x4 via 2 cndmask levels
#define EXTR(A) (jhi ? (jlo ? (A)[3] : (A)[2]) : (jlo ? (A)[1] : (A)[0]))

// stage one 16-step x chunk: slot(step s, kgroup g, batch bb) = x[k=g*8..+7][bb] packed f16
#define STAGE(c) do {                                                               \
    if (tid < 256) {                                                                \
        const int t0_ = (c) * 16;                                                   \
        const int s_ = tid >> 4, g_ = (tid >> 2) & 3, bb_ = tid & 3;                \
        const float* p_ = x + (size_t)(bbase + bb_) * (SS * II)                     \
                          + (size_t)(t0_ + s_) * II + g_ * 8;                       \
        float4 v0_ = ((const float4*)p_)[0];                                        \
        float4 v1_ = ((const float4*)p_)[1];                                        \
        u32x4e wv_ = { pk(v0_.x, v0_.y), pk(v0_.z, v0_.w),                          \
                       pk(v1_.x, v1_.y), pk(v1_.z, v1_.w) };                        \
        *(u32x4e*)((char*)&xsb[(c) & 1][s_][0] + (g_ * 4 + bb_) * 16) = wv_;        \
    } } while (0)

__global__ __launch_bounds__(512, 1) void lstm_mfma(
    const float* __restrict__ x,
    const float* __restrict__ h_in, const float* __restrict__ c_in,
    const float* __restrict__ Wih0, const float* __restrict__ Whh0,
    const float* __restrict__ bih0, const float* __restrict__ bhh0,
    const float* __restrict__ Wih1, const float* __restrict__ Whh1,
    const float* __restrict__ bih1, const float* __restrict__ bhh1,
    const float* __restrict__ Wh, const float* __restrict__ bh,
    float* __restrict__ out)
{
    // hbuf[parity][layer]: packed f16 h, slot byte = ((u>>3)*4 + bb)*16 + (u&7)*2
    __shared__ uint32_t hbuf[2][2][128];
    __shared__ uint32_t xsb[2][16][64];     // [chunk parity][step][(kgroup*4+bb)*4 words]
    __shared__ float    pbuf[64][4];        // probs ring [t&63][batch]

    const int tid = threadIdx.x;
    const int w   = tid >> 6, L = tid & 63;
    const int wl  = w & 3;
    const int g16 = L >> 4, b16 = L & 15;
    const int bb  = b16 & 3, j = b16 >> 2;
    const int isL1 = (w >= 4);
    const int u    = 16 * wl + g16 * 4 + j;     // lane's owned unit
    const int bbase = blockIdx.x * TB;
    const int loff  = isL1 ? 16384 : 0;
    const bool jlo = (j & 1) != 0, jhi = (j & 2) != 0;
    const int hoff = ((u >> 3) * 4 + bb) * 16 + (u & 7) * 2;

    // ---- initial state: lane owns cell (u, bb) of its layer ----
    float hst = h_in[loff + (size_t)(bbase + bb) * 64 + u];
    float cst = c_in[loff + (size_t)(bbase + bb) * 64 + u];
    {
        float o = __shfl_xor(hst, 4);           // partner unit u^1 (j^1, lane distance 4)
        if (!jlo) *(uint32_t*)((char*)&hbuf[1][isL1][0] + hoff) = pk(hst, o);
    }
    STAGE(0);
    __syncthreads();

    if (!isL1) {
        // ========== L0 waves: 16 units (16wl..+15) x 4 gate tiles ==========
        frag aH[4][2], aX[4];
        f32x4 bias4[4];
        #pragma unroll
        for (int t = 0; t < 4; ++t) {
            const int arow = t * 64 + 16 * wl + b16;
            aH[t][0] = load8(Whh0 + arow * 64 + g16 * 8);
            aH[t][1] = load8(Whh0 + arow * 64 + 32 + g16 * 8);
            aX[t]    = load8(Wih0 + arow * 32 + g16 * 8);
            const int brow = t * 64 + 16 * wl + g16 * 4;
            float4 q1 = *(const float4*)(bih0 + brow);
            float4 q2 = *(const float4*)(bhh0 + brow);
            bias4[t] = (f32x4){q1.x + q2.x, q1.y + q2.y, q1.z + q2.z, q1.w + q2.w};
        }

        #pragma unroll 1
        for (int it = 0; it <= SS + 1; ++it) {
            if (it < SS) {
                const char* hb = (const char*)&hbuf[(it + 1) & 1][0][0];   // h0(it-1)
                frag bh0, bh1, bx;
                bh0.v = *(const f16x8*)(hb + (g16 * 4 + bb) * 16);
                bh1.v = *(const f16x8*)(hb + ((4 + g16) * 4 + bb) * 16);
                bx.v  = *(const f16x8*)((const char*)&xsb[(it >> 4) & 1][it & 15][0]
                                        + (g16 * 4 + bb) * 16);
                f32x4 a0 = bias4[0], a1 = bias4[1], a2 = bias4[2], a3 = bias4[3];
                a0 = MFMA(aH[0][0], bh0, a0); a1 = MFMA(aH[1][0], bh0, a1);
                a2 = MFMA(aH[2][0], bh0, a2); a3 = MFMA(aH[3][0], bh0, a3);
                a0 = MFMA(aH[0][1], bh1, a0); a1 = MFMA(aH[1][1], bh1, a1);
                a2 = MFMA(aH[2][1], bh1, a2); a3 = MFMA(aH[3][1], bh1, a3);
                a0 = MFMA(aX[0], bx, a0);     a1 = MFMA(aX[1], bx, a1);
                a2 = MFMA(aX[2], bx, a2);     a3 = MFMA(aX[3], bx, a3);
                // one cell per lane
                float gi = sigm(EXTR(a0)), gf = sigm(EXTR(a1));
                float gg = tanh_(EXTR(a2)), go = sigm(EXTR(a3));
                cst = gf * cst + gi * gg;
                hst = go * tanh_(cst);
                float o = __shfl_xor(hst, 4);
                if (!jlo) *(uint32_t*)((char*)&hbuf[it & 1][0][0] + hoff) = pk(hst, o);
            }
            if ((it & 15) == 0 && it + 16 < SS) STAGE((it >> 4) + 1);
            __syncthreads();
        }
    } else {
        // ========== L1 waves (1-step skew): at iter it compute step it-1 ==========
        frag aI[4][2], aR[4][2];
        f32x4 bias4[4];
        #pragma unroll
        for (int t = 0; t < 4; ++t) {
            const int arow = t * 64 + 16 * wl + b16;
            aI[t][0] = load8(Wih1 + arow * 64 + g16 * 8);
            aI[t][1] = load8(Wih1 + arow * 64 + 32 + g16 * 8);
            aR[t][0] = load8(Whh1 + arow * 64 + g16 * 8);
            aR[t][1] = load8(Whh1 + arow * 64 + 32 + g16 * 8);
            const int brow = t * 64 + 16 * wl + g16 * 4;
            float4 q1 = *(const float4*)(bih1 + brow);
            float4 q2 = *(const float4*)(bhh1 + brow);
            bias4[t] = (f32x4){q1.x + q2.x, q1.y + q2.y, q1.z + q2.z, q1.w + q2.w};
        }
        frag whA = load8(Wh + g16 * 8);
        frag whB = load8(Wh + 32 + g16 * 8);
        const float bhs = bh[0];

        #pragma unroll 1
        for (int it = 0; it <= SS + 1; ++it) {
            frag b1, b1k;
            if (it >= 1) {                                   // h1(it-2)
                const char* h1b = (const char*)&hbuf[it & 1][1][0];
                b1.v  = *(const f16x8*)(h1b + (g16 * 4 + bb) * 16);
                b1k.v = *(const f16x8*)(h1b + ((4 + g16) * 4 + bb) * 16);
            }
            if (it >= 1 && it <= SS) {
                const char* h0b = (const char*)&hbuf[(it + 1) & 1][0][0];  // h0(it-1)
                frag b0, b0k;
                b0.v  = *(const f16x8*)(h0b + (g16 * 4 + bb) * 16);
                b0k.v = *(const f16x8*)(h0b + ((4 + g16) * 4 + bb) * 16);
                f32x4 a0 = bias4[0], a1 = bias4[1], a2 = bias4[2], a3 = bias4[3];
                a0 = MFMA(aI[0][0], b0, a0);  a1 = MFMA(aI[1][0], b0, a1);
                a2 = MFMA(aI[2][0], b0, a2);  a3 = MFMA(aI[3][0], b0, a3);
                a0 = MFMA(aI[0][1], b0k, a0); a1 = MFMA(aI[1][1], b0k, a1);
                a2 = MFMA(aI[2][1], b0k, a2); a3 = MFMA(aI[3][1], b0k, a3);
                a0 = MFMA(aR[0][0], b1, a0);  a1 = MFMA(aR[1][0], b1, a1);
                a2 = MFMA(aR[2][0], b1, a2);  a3 = MFMA(aR[3][0], b1, a3);
                a0 = MFMA(aR[0][1], b1k, a0); a1 = MFMA(aR[1][1], b1k, a1);
                a2 = MFMA(aR[2][1], b1k, a2); a3 = MFMA(aR[3][1], b1k, a3);
                float gi = sigm(EXTR(a0)), gf = sigm(EXTR(a1));
                float gg = tanh_(EXTR(a2)), go = sigm(EXTR(a3));
                cst = gf * cst + gi * gg;
                hst = go * tanh_(cst);
                float o = __shfl_xor(hst, 4);
                if (!jlo) *(uint32_t*)((char*)&hbuf[(it + 1) & 1][1][0] + hoff) = pk(hst, o);
            }
            if (w == 4 && it >= 2) {
                // head for step t = it-2, using h1(it-2) frags b1/b1k
                float pv = 0.f;
                #pragma unroll
                for (int i = 0; i < 4; ++i) {
                    pv = fdot2(whA.w[i], b1.w[i], pv);
                    pv = fdot2(whB.w[i], b1k.w[i], pv);
                }
                pv += __shfl_xor(pv, 16);
                pv += __shfl_xor(pv, 32);
                pv = sigm(pv + bhs);
                const int t = it - 2;
                if (L < 4) pbuf[t & 63][L] = pv;
                if ((t & 63) == 63) {                       // coalesced flush of 64 steps
                    const int tbase = t & ~63;
                    const int fb = L >> 4, fs = (L & 15) * 4;
                    float4 vv = make_float4(pbuf[fs][fb], pbuf[fs + 1][fb],
                                            pbuf[fs + 2][fb], pbuf[fs + 3][fb]);
                    *(float4*)(out + (size_t)(bbase + fb) * SS + tbase + fs) = vv;
                }
            }
            __syncthreads();
        }
    }

    // ---- final states: h at 524288 (2,256,64), c at 557056 ----
    out[524288 + loff + (size_t)(bbase + bb) * 64 + u] = hst;
    out[557056 + loff + (size_t)(bbase + bb) * 64 + u] = cst;
}

extern "C" void kernel_launch(void* const* d_in, const int* in_sizes, int n_in,
                              void* d_out, int out_size, void* d_ws, size_t ws_size,
                              hipStream_t stream) {
    const float* x    = (const float*)d_in[0];
    const float* h0   = (const float*)d_in[1];
    const float* c0   = (const float*)d_in[2];
    const float* Wih0 = (const float*)d_in[3];
    const float* Whh0 = (const float*)d_in[4];
    const float* bih0 = (const float*)d_in[5];
    const float* bhh0 = (const float*)d_in[6];
    const float* Wih1 = (const float*)d_in[7];
    const float* Whh1 = (const float*)d_in[8];
    const float* bih1 = (const float*)d_in[9];
    const float* bhh1 = (const float*)d_in[10];
    const float* Wh   = (const float*)d_in[11];
    const float* bh   = (const float*)d_in[12];
    float* out = (float*)d_out;

    hipLaunchKernelGGL(lstm_mfma, dim3(256 / TB), dim3(512), 0, stream,
                       x, h0, c0, Wih0, Whh0, bih0, bhh0,
                       Wih1, Whh1, bih1, bhh1, Wh, bh, out);
}

// Round 11
// 1203.107 us; speedup vs baseline: 2.5937x; 1.1547x over previous
//
#include <hip/hip_runtime.h>
#include <math.h>
#include <stdint.h>

#define SS 2048
#define II 32
#define TB 4

typedef _Float16 f16x8  __attribute__((ext_vector_type(8)));
typedef float    f32x4  __attribute__((ext_vector_type(4)));
typedef uint32_t u32x4e __attribute__((ext_vector_type(4)));
typedef _Float16 f16x2  __attribute__((ext_vector_type(2)));
typedef __fp16   g16x2  __attribute__((ext_vector_type(2)));

union uhc { uint32_t u; f16x2 a; g16x2 b; };
union frag { f16x8 v; uint32_t w[4]; u32x4e q; };

__device__ __forceinline__ uint32_t pk(float x, float y) {
    uhc c; c.b = __builtin_amdgcn_cvt_pkrtz(x, y); return c.u;
}
__device__ __forceinline__ float fdot2(uint32_t a, uint32_t b, float c) {
    uhc x, y; x.u = a; y.u = b;
#if __has_builtin(__builtin_amdgcn_fdot2)
    return __builtin_amdgcn_fdot2(x.a, y.a, c, false);
#else
    return c + (float)x.a.x * (float)y.a.x + (float)x.a.y * (float)y.a.y;
#endif
}
__device__ __forceinline__ float sigm(float x) { return __builtin_amdgcn_rcpf(1.f + __expf(-x)); }
__device__ __forceinline__ float tanh_(float x) {
    x = fminf(fmaxf(x, -15.f), 15.f);
    float e = __expf(-2.f * x);
    return (1.f - e) * __builtin_amdgcn_rcpf(1.f + e);
}
__device__ __forceinline__ frag load8(const float* p) {
    float4 v0 = ((const float4*)p)[0];
    float4 v1 = ((const float4*)p)[1];
    frag f;
    f.w[0] = pk(v0.x, v0.y); f.w[1] = pk(v0.z, v0.w);
    f.w[2] = pk(v1.x, v1.y); f.w[3] = pk(v1.z, v1.w);
    return f;
}
#define MFMA(A, B, C) __builtin_amdgcn_mfma_f32_16x16x32_f16((A).v, (B).v, (C), 0, 0, 0)
#define EXTR(A) (jhi ? (jlo ? (A)[3] : (A)[2]) : (jlo ? (A)[1] : (A)[0]))

__global__ __launch_bounds__(512, 1) void lstm_mfma(
    const float* __restrict__ x,
    const float* __restrict__ h_in, const float* __restrict__ c_in,
    const float* __restrict__ Wih0, const float* __restrict__ Whh0,
    const float* __restrict__ bih0, const float* __restrict__ bhh0,
    const float* __restrict__ Wih1, const float* __restrict__ Whh1,
    const float* __restrict__ bih1, const float* __restrict__ bhh1,
    const float* __restrict__ Wh, const float* __restrict__ bh,
    float* __restrict__ out)
{
    // hbuf[parity][layer]: packed f16 h, cell slot byte = ((u>>3)*4 + bb)*16 + (u&7)*2
    __shared__ uint32_t hbuf[2][2][128];
    __shared__ uint32_t xsb[2][16][64];     // [chunk parity][step][(kgroup*4+bb)*4 words]
    __shared__ float    pbuf[64][4];        // probs ring [t&63][batch]

    const int tid = threadIdx.x;
    const int w   = tid >> 6, L = tid & 63;
    const int wl  = w & 3;
    const int g16 = L >> 4, b16 = L & 15;
    const int bb  = b16 & 3, j = b16 >> 2;
    const int isL1 = (w >= 4);
    const int u    = 16 * wl + g16 * 4 + j;     // lane's owned unit
    const int bbase = blockIdx.x * TB;
    const int loff  = isL1 ? 16384 : 0;
    const bool jlo = (j & 1) != 0, jhi = (j & 2) != 0;
    const int hoff = ((u >> 3) * 4 + bb) * 16 + (u & 7) * 2;   // this lane's own f16 slot

    const f32x4 zf4 = {0.f, 0.f, 0.f, 0.f};

    // ---- initial state: lane owns cell (u, bb) of its layer ----
    float hst = h_in[loff + (size_t)(bbase + bb) * 64 + u];
    float cst = c_in[loff + (size_t)(bbase + bb) * 64 + u];
    *(__fp16*)((char*)&hbuf[1][isL1][0] + hoff) = (__fp16)hst;   // h(-1)

    // ---- stage chunk 0 synchronously (prologue only) ----
    if (tid < 256) {
        const int s_ = tid >> 4, g_ = (tid >> 2) & 3, bb_ = tid & 3;
        const float* p_ = x + (size_t)(bbase + bb_) * (SS * II) + (size_t)s_ * II + g_ * 8;
        float4 v0_ = ((const float4*)p_)[0];
        float4 v1_ = ((const float4*)p_)[1];
        u32x4e wv_ = { pk(v0_.x, v0_.y), pk(v0_.z, v0_.w), pk(v1_.x, v1_.y), pk(v1_.z, v1_.w) };
        *(u32x4e*)((char*)&xsb[0][s_][0] + (g_ * 4 + bb_) * 16) = wv_;
    }
    __syncthreads();

    if (!isL1) {
        // ========== L0 waves: 16 units (16wl..+15) x 4 gate tiles; w0 also runs the head ==========
        frag aH[4][2], aX[4];
        f32x4 bias4[4];
        #pragma unroll
        for (int t = 0; t < 4; ++t) {
            const int arow = t * 64 + 16 * wl + b16;
            aH[t][0] = load8(Whh0 + arow * 64 + g16 * 8);
            aH[t][1] = load8(Whh0 + arow * 64 + 32 + g16 * 8);
            aX[t]    = load8(Wih0 + arow * 32 + g16 * 8);
            const int brow = t * 64 + 16 * wl + g16 * 4;
            float4 q1 = *(const float4*)(bih0 + brow);
            float4 q2 = *(const float4*)(bhh0 + brow);
            bias4[t] = (f32x4){q1.x + q2.x, q1.y + q2.y, q1.z + q2.z, q1.w + q2.w};
        }
        // head constants (wave 0)
        frag whA = load8(Wh + g16 * 8);
        frag whB = load8(Wh + 32 + g16 * 8);
        const float bhs = bh[0];

        // split-stage registers (x chunk in flight)
        float4 xr0, xr1;
        const int s_ = tid >> 4, g_ = (tid >> 2) & 3, bb_ = tid & 3;
        const float* xsrc_base = x + (size_t)(bbase + bb_) * (SS * II) + (size_t)s_ * II + g_ * 8;

        #pragma unroll 2
        for (int it = 0; it <= SS + 1; ++it) {
            if ((it & 15) == 0 && it + 16 < SS) {            // T14: issue loads early
                const float* p_ = xsrc_base + (size_t)(((it >> 4) + 1) * 16) * II;
                xr0 = ((const float4*)p_)[0];
                xr1 = ((const float4*)p_)[1];
            }
            if (it < SS) {
                const char* hb = (const char*)&hbuf[(it + 1) & 1][0][0];   // h0(it-1)
                frag bh0, bh1, bx;
                bh0.v = *(const f16x8*)(hb + (g16 * 4 + bb) * 16);
                bh1.v = *(const f16x8*)(hb + ((4 + g16) * 4 + bb) * 16);
                bx.v  = *(const f16x8*)((const char*)&xsb[(it >> 4) & 1][it & 15][0]
                                        + (g16 * 4 + bb) * 16);
                // two parallel chains per gate tile, then one vector add
                f32x4 p0 = bias4[0], p1 = bias4[1], p2 = bias4[2], p3 = bias4[3];
                p0 = MFMA(aH[0][0], bh0, p0); p1 = MFMA(aH[1][0], bh0, p1);
                p2 = MFMA(aH[2][0], bh0, p2); p3 = MFMA(aH[3][0], bh0, p3);
                p0 = MFMA(aX[0], bx, p0);     p1 = MFMA(aX[1], bx, p1);
                p2 = MFMA(aX[2], bx, p2);     p3 = MFMA(aX[3], bx, p3);
                f32x4 q0 = MFMA(aH[0][1], bh1, zf4), q1 = MFMA(aH[1][1], bh1, zf4);
                f32x4 q2 = MFMA(aH[2][1], bh1, zf4), q3 = MFMA(aH[3][1], bh1, zf4);
                f32x4 a0 = p0 + q0, a1 = p1 + q1, a2 = p2 + q2, a3 = p3 + q3;
                float gi = sigm(EXTR(a0)), gf = sigm(EXTR(a1));
                float gg = tanh_(EXTR(a2)), go = sigm(EXTR(a3));
                cst = gf * cst + gi * gg;
                hst = go * tanh_(cst);
                *(__fp16*)((char*)&hbuf[it & 1][0][0] + hoff) = (__fp16)hst;   // h0(it)
            }
            if (w == 0 && it >= 2) {
                // head for step t = it-2 from h1(it-2)
                const char* h1b = (const char*)&hbuf[it & 1][1][0];
                frag b1, b1k;
                b1.v  = *(const f16x8*)(h1b + (g16 * 4 + bb) * 16);
                b1k.v = *(const f16x8*)(h1b + ((4 + g16) * 4 + bb) * 16);
                float pv = 0.f;
                #pragma unroll
                for (int i = 0; i < 4; ++i) {
                    pv = fdot2(whA.w[i], b1.w[i], pv);
                    pv = fdot2(whB.w[i], b1k.w[i], pv);
                }
                pv += __shfl_xor(pv, 16);
                pv += __shfl_xor(pv, 32);
                pv = sigm(pv + bhs);
                const int t = it - 2;
                if (L < 4) pbuf[t & 63][L] = pv;
                if ((t & 63) == 63) {
                    const int tbase = t & ~63;
                    const int fb = L >> 4, fs = (L & 15) * 4;
                    float4 vv = make_float4(pbuf[fs][fb], pbuf[fs + 1][fb],
                                            pbuf[fs + 2][fb], pbuf[fs + 3][fb]);
                    *(float4*)(out + (size_t)(bbase + fb) * SS + tbase + fs) = vv;
                }
            }
            if ((it & 15) == 8 && it + 8 < SS) {             // T14: write staged chunk late
                const int cn = (it >> 4) + 1;
                u32x4e wv_ = { pk(xr0.x, xr0.y), pk(xr0.z, xr0.w),
                               pk(xr1.x, xr1.y), pk(xr1.z, xr1.w) };
                *(u32x4e*)((char*)&xsb[cn & 1][s_][0] + (g_ * 4 + bb_) * 16) = wv_;
            }
            __syncthreads();
        }
    } else {
        // ========== L1 waves (1-step skew): at iter it compute step it-1 ==========
        frag aI[4][2], aR[4][2];
        f32x4 bias4[4];
        #pragma unroll
        for (int t = 0; t < 4; ++t) {
            const int arow = t * 64 + 16 * wl + b16;
            aI[t][0] = load8(Wih1 + arow * 64 + g16 * 8);
            aI[t][1] = load8(Wih1 + arow * 64 + 32 + g16 * 8);
            aR[t][0] = load8(Whh1 + arow * 64 + g16 * 8);
            aR[t][1] = load8(Whh1 + arow * 64 + 32 + g16 * 8);
            const int brow = t * 64 + 16 * wl + g16 * 4;
            float4 q1 = *(const float4*)(bih1 + brow);
            float4 q2 = *(const float4*)(bhh1 + brow);
            bias4[t] = (f32x4){q1.x + q2.x, q1.y + q2.y, q1.z + q2.z, q1.w + q2.w};
        }

        #pragma unroll 2
        for (int it = 0; it <= SS + 1; ++it) {
            if (it >= 1 && it <= SS) {
                const char* h1b = (const char*)&hbuf[it & 1][1][0];        // h1(it-2)
                const char* h0b = (const char*)&hbuf[(it + 1) & 1][0][0];  // h0(it-1)
                frag b0, b0k, b1, b1k;
                b0.v  = *(const f16x8*)(h0b + (g16 * 4 + bb) * 16);
                b0k.v = *(const f16x8*)(h0b + ((4 + g16) * 4 + bb) * 16);
                b1.v  = *(const f16x8*)(h1b + (g16 * 4 + bb) * 16);
                b1k.v = *(const f16x8*)(h1b + ((4 + g16) * 4 + bb) * 16);
                // two parallel chains per gate tile
                f32x4 p0 = bias4[0], p1 = bias4[1], p2 = bias4[2], p3 = bias4[3];
                p0 = MFMA(aI[0][0], b0, p0);  p1 = MFMA(aI[1][0], b0, p1);
                p2 = MFMA(aI[2][0], b0, p2);  p3 = MFMA(aI[3][0], b0, p3);
                p0 = MFMA(aR[0][0], b1, p0);  p1 = MFMA(aR[1][0], b1, p1);
                p2 = MFMA(aR[2][0], b1, p2);  p3 = MFMA(aR[3][0], b1, p3);
                f32x4 q0 = MFMA(aI[0][1], b0k, zf4), q1 = MFMA(aI[1][1], b0k, zf4);
                f32x4 q2 = MFMA(aI[2][1], b0k, zf4), q3 = MFMA(aI[3][1], b0k, zf4);
                q0 = MFMA(aR[0][1], b1k, q0); q1 = MFMA(aR[1][1], b1k, q1);
                q2 = MFMA(aR[2][1], b1k, q2); q3 = MFMA(aR[3][1], b1k, q3);
                f32x4 a0 = p0 + q0, a1 = p1 + q1, a2 = p2 + q2, a3 = p3 + q3;
                float gi = sigm(EXTR(a0)), gf = sigm(EXTR(a1));
                float gg = tanh_(EXTR(a2)), go = sigm(EXTR(a3));
                cst = gf * cst + gi * gg;
                hst = go * tanh_(cst);
                *(__fp16*)((char*)&hbuf[(it + 1) & 1][1][0] + hoff) = (__fp16)hst;  // h1(it-1)
            }
            __syncthreads();
        }
    }

    // ---- final states: h at 524288 (2,256,64), c at 557056 ----
    out[524288 + loff + (size_t)(bbase + bb) * 64 + u] = hst;
    out[557056 + loff + (size_t)(bbase + bb) * 64 + u] = cst;
}

extern "C" void kernel_launch(void* const* d_in, const int* in_sizes, int n_in,
                              void* d_out, int out_size, void* d_ws, size_t ws_size,
                              hipStream_t stream) {
    const float* x    = (const float*)d_in[0];
    const float* h0   = (const float*)d_in[1];
    const float* c0   = (const float*)d_in[2];
    const float* Wih0 = (const float*)d_in[3];
    const float* Whh0 = (const float*)d_in[4];
    const float* bih0 = (const float*)d_in[5];
    const float* bhh0 = (const float*)d_in[6];
    const float* Wih1 = (const float*)d_in[7];
    const float* Whh1 = (const float*)d_in[8];
    const float* bih1 = (const float*)d_in[9];
    const float* bhh1 = (const float*)d_in[10];
    const float* Wh   = (const float*)d_in[11];
    const float* bh   = (const float*)d_in[12];
    float* out = (float*)d_out;

    hipLaunchKernelGGL(lstm_mfma, dim3(256 / TB), dim3(512), 0, stream,
                       x, h0, c0, Wih0, Whh0, bih0, bhh0,
                       Wih1, Whh1, bih1, bhh1, Wh, bh, out);
}